// Round 2
// baseline (355.150 us; speedup 1.0000x reference)
//
#include <hip/hip_runtime.h>
#include <math.h>

#define M_OBJ 4
#define N_PTS 3072
#define K_NN  10
#define NSLOT (M_OBJ - 1)   // other-object slots per query object
#define QCHUNK 256          // query points per block

// Combined transform T = inv(plane_T) @ est_T  (3x4, row-major semantics).
// plane_T is orthonormal-rigid: inv = [R^T | -R^T t], bottom row (0,0,0,1).
__device__ inline void make_T(const float* __restrict__ E,   // est_T[m], 4x4 row-major
                              const float* __restrict__ P,   // plane_T, 4x4 row-major
                              float T[3][4]) {
    float Pi[3][4];
#pragma unroll
    for (int i = 0; i < 3; ++i) {
#pragma unroll
        for (int j = 0; j < 3; ++j) Pi[i][j] = P[j * 4 + i];       // R^T
        Pi[i][3] = -(P[0 * 4 + i] * P[3] + P[1 * 4 + i] * P[7] + P[2 * 4 + i] * P[11]);
    }
#pragma unroll
    for (int i = 0; i < 3; ++i) {
#pragma unroll
        for (int j = 0; j < 4; ++j) {
            float acc = (j == 3) ? Pi[i][3] : 0.0f;
#pragma unroll
            for (int kk = 0; kk < 3; ++kk) acc += Pi[i][kk] * E[kk * 4 + j];
            T[i][j] = acc;
        }
    }
}

// One block per (ordered pair q!=r, 256-query chunk).
// Stages ref object's transformed points in LDS, per-thread top-10 scan.
__global__ __launch_bounds__(QCHUNK) void pair_kernel(
        const float* __restrict__ points,   // [M][N][6]
        const float* __restrict__ estT,     // [M][4][4]
        const float* __restrict__ planeT,   // [4][4]
        float* __restrict__ pair_sd) {      // [M][NSLOT][N]
    __shared__ float4 sref[N_PTS];          // 48 KiB

    const int pidx = blockIdx.x;            // 0..11
    const int q  = pidx / NSLOT;
    const int rs = pidx % NSLOT;
    const int r  = rs + (rs >= q ? 1 : 0);
    const int tid = threadIdx.x;

    float Tq[3][4], Tr[3][4];
    make_T(estT + q * 16, planeT, Tq);
    make_T(estT + r * 16, planeT, Tr);

    // Stage reference object's points (transformed to plane frame) into LDS.
    for (int j = tid; j < N_PTS; j += QCHUNK) {
        const float* p = points + (size_t)(r * N_PTS + j) * 6;
        float x = p[0], y = p[1], z = p[2];
        float px = Tr[0][0] * x + Tr[0][1] * y + Tr[0][2] * z + Tr[0][3];
        float py = Tr[1][0] * x + Tr[1][1] * y + Tr[1][2] * z + Tr[1][3];
        float pz = Tr[2][0] * x + Tr[2][1] * y + Tr[2][2] * z + Tr[2][3];
        sref[j] = make_float4(px, py, pz, 0.0f);
    }
    __syncthreads();

    // This thread's query point.
    const int nq = blockIdx.y * QCHUNK + tid;
    const float* qp = points + (size_t)(q * N_PTS + nq) * 6;
    float x = qp[0], y = qp[1], z = qp[2];
    float qx = Tq[0][0] * x + Tq[0][1] * y + Tq[0][2] * z + Tq[0][3];
    float qy = Tq[1][0] * x + Tq[1][1] * y + Tq[1][2] * z + Tq[1][3];
    float qz = Tq[2][0] * x + Tq[2][1] * y + Tq[2][2] * z + Tq[2][3];

    // Top-K nearest, sorted DESCENDING (best[0] = worst of the kept K,
    // best[K_NN-1] = nearest).
    float best[K_NN];
    int   bidx[K_NN];
#pragma unroll
    for (int i = 0; i < K_NN; ++i) { best[i] = 3.4e38f; bidx[i] = 0; }

    for (int j = 0; j < N_PTS; ++j) {
        float4 p = sref[j];                 // uniform address -> LDS broadcast
        float dx = p.x - qx, dy = p.y - qy, dz = p.z - qz;
        float sq = dx * dx + dy * dy + dz * dz;
        if (sq < best[0]) {
            best[0] = sq; bidx[0] = j;
            // one bubble pass restores descending order
#pragma unroll
            for (int i = 0; i < K_NN - 1; ++i) {
                if (best[i] < best[i + 1]) {
                    float tb = best[i]; best[i] = best[i + 1]; best[i + 1] = tb;
                    int   ti = bidx[i]; bidx[i] = bidx[i + 1]; bidx[i + 1] = ti;
                }
            }
        }
    }

    // Inside/outside vote over the 10 nearest. grad normalization dropped:
    // it cannot change the sign of dot(normal, grad).
    int votes = 0;
#pragma unroll
    for (int i = 0; i < K_NN; ++i) {
        int j = bidx[i];
        float4 p = sref[j];
        float gx = p.x - qx, gy = p.y - qy, gz = p.z - qz;
        const float* np_ = points + (size_t)(r * N_PTS + j) * 6 + 3;
        float d = np_[0] * gx + np_[1] * gy + np_[2] * gz;
        votes += (d > 0.0f) ? 1 : 0;
    }

    float d0 = sqrtf(fmaxf(best[K_NN - 1], 0.0f));
    float sd = (votes > 8) ? -d0 : d0;
    pair_sd[((size_t)q * NSLOT + rs) * N_PTS + nq] = sd;
}

// Min over the 3 other-object signed distances and the plane distance; write
// both outputs (signed_distance fp32, intersects as 0/1 fp32).
__global__ __launch_bounds__(256) void reduce_kernel(
        const float* __restrict__ points,
        const float* __restrict__ estT,
        const float* __restrict__ planeT,
        const float* __restrict__ pair_sd,
        float* __restrict__ out) {
    int i = blockIdx.x * blockDim.x + threadIdx.x;
    if (i >= M_OBJ * N_PTS) return;
    int m = i / N_PTS, n = i % N_PTS;

    float T[3][4];
    make_T(estT + m * 16, planeT, T);
    const float* p = points + (size_t)i * 6;
    float zpl = T[2][0] * p[0] + T[2][1] * p[1] + T[2][2] * p[2] + T[2][3];

    float sd = zpl;
#pragma unroll
    for (int rs = 0; rs < NSLOT; ++rs)
        sd = fminf(sd, pair_sd[((size_t)m * NSLOT + rs) * N_PTS + n]);

    out[i] = sd;
    out[M_OBJ * N_PTS + i] = (sd < -0.01f) ? 1.0f : 0.0f;
}

extern "C" void kernel_launch(void* const* d_in, const int* in_sizes, int n_in,
                              void* d_out, int out_size, void* d_ws, size_t ws_size,
                              hipStream_t stream) {
    const float* points = (const float*)d_in[0];   // [4][3072][6]
    const float* estT   = (const float*)d_in[1];   // [4][4][4]
    const float* planeT = (const float*)d_in[2];   // [4][4]
    // d_in[3] = k (always 10 here)

    float* pair_sd = (float*)d_ws;                 // [4][3][3072] = 147 KiB

    dim3 gridB(M_OBJ * NSLOT, N_PTS / QCHUNK);     // 12 x 12
    pair_kernel<<<gridB, QCHUNK, 0, stream>>>(points, estT, planeT, pair_sd);

    int total = M_OBJ * N_PTS;
    reduce_kernel<<<(total + 255) / 256, 256, 0, stream>>>(points, estT, planeT,
                                                           pair_sd, (float*)d_out);
}

// Round 4
// 161.800 us; speedup vs baseline: 2.1950x; 2.1950x over previous
//
#include <hip/hip_runtime.h>
#include <math.h>

#define M_OBJ 4
#define N_PTS 3072
#define K_NN  10
#define NSLOT (M_OBJ - 1)
#define QPB   64            // queries per block
#define SEG   4             // reference segments (one per wave)
#define SEGN  (N_PTS / SEG) // 768 points per segment

// T = inv(plane_T) @ est_T (3x4). plane_T is orthonormal-rigid: inv = [R^T|-R^T t].
__device__ inline void make_T(const float* __restrict__ E,
                              const float* __restrict__ P,
                              float T[3][4]) {
    float Pi[3][4];
#pragma unroll
    for (int i = 0; i < 3; ++i) {
#pragma unroll
        for (int j = 0; j < 3; ++j) Pi[i][j] = P[j * 4 + i];
        Pi[i][3] = -(P[0 * 4 + i] * P[3] + P[1 * 4 + i] * P[7] + P[2 * 4 + i] * P[11]);
    }
#pragma unroll
    for (int i = 0; i < 3; ++i) {
#pragma unroll
        for (int j = 0; j < 4; ++j) {
            float acc = (j == 3) ? Pi[i][3] : 0.0f;
#pragma unroll
            for (int kk = 0; kk < 3; ++kk) acc += Pi[i][kk] * E[kk * 4 + j];
            T[i][j] = acc;
        }
    }
}

// Block = 256 threads: wave s scans ref segment s for the block's 64 queries.
// Partial top-10s merged via LDS by wave 0.
__global__ __launch_bounds__(256, 2) void pair_kernel(
        const float* __restrict__ points,   // [M][N][6]
        const float* __restrict__ estT,     // [M][4][4]
        const float* __restrict__ planeT,   // [4][4]
        float* __restrict__ pair_sd) {      // [M][NSLOT][N]
    __shared__ float4 sref[N_PTS];          // 48 KiB
    __shared__ float  msq [256 * K_NN];     // 10 KiB
    __shared__ int    midx[256 * K_NN];     // 10 KiB

    const int pidx  = blockIdx.x;           // 0..11
    const int q     = pidx / NSLOT;
    const int rs    = pidx % NSLOT;
    const int r     = rs + (rs >= q ? 1 : 0);
    const int tid   = threadIdx.x;
    const int seg   = tid >> 6;             // wave id = segment
    const int qlane = tid & 63;

    float Tq[3][4], Tr[3][4];
    make_T(estT + q * 16, planeT, Tq);
    make_T(estT + r * 16, planeT, Tr);

    // Stage reference object's transformed points into LDS (all 256 threads).
    for (int j = tid; j < N_PTS; j += 256) {
        const float* p = points + (size_t)(r * N_PTS + j) * 6;
        float2 xy = *(const float2*)p;      // 24B rows are 8B-aligned
        float  z  = p[2];
        float px = Tr[0][0] * xy.x + Tr[0][1] * xy.y + Tr[0][2] * z + Tr[0][3];
        float py = Tr[1][0] * xy.x + Tr[1][1] * xy.y + Tr[1][2] * z + Tr[1][3];
        float pz = Tr[2][0] * xy.x + Tr[2][1] * xy.y + Tr[2][2] * z + Tr[2][3];
        sref[j] = make_float4(px, py, pz, 0.0f);
    }
    __syncthreads();

    // This thread's query point (same query for the 4 threads tid%64 equal).
    const int nq = blockIdx.y * QPB + qlane;
    const float* qp = points + (size_t)(q * N_PTS + nq) * 6;
    float2 qxy = *(const float2*)qp;
    float  qzz = qp[2];
    const float qx = Tq[0][0] * qxy.x + Tq[0][1] * qxy.y + Tq[0][2] * qzz + Tq[0][3];
    const float qy = Tq[1][0] * qxy.x + Tq[1][1] * qxy.y + Tq[1][2] * qzz + Tq[1][3];
    const float qz = Tq[2][0] * qxy.x + Tq[2][1] * qxy.y + Tq[2][2] * qzz + Tq[2][3];

    // Top-K (squared), sorted DESCENDING: best[0]=worst kept, best[9]=nearest.
    float best[K_NN];
    int   bidx[K_NN];
#pragma unroll
    for (int i = 0; i < K_NN; ++i) { best[i] = 3.4e38f; bidx[i] = 0; }

    // Unroll-8 scan of this wave's 768-point segment: 8 independent
    // loads+distances, min-tree, rare branch into the sorted insert.
    const int j0 = seg * SEGN;
    for (int jb = 0; jb < SEGN; jb += 8) {
        const int jj = j0 + jb;
        float sq[8];
#pragma unroll
        for (int u = 0; u < 8; ++u) {
            float4 p = sref[jj + u];
            float dx = p.x - qx, dy = p.y - qy, dz = p.z - qz;
            sq[u] = fmaf(dx, dx, fmaf(dy, dy, dz * dz));
        }
        float m01 = fminf(sq[0], sq[1]), m23 = fminf(sq[2], sq[3]);
        float m45 = fminf(sq[4], sq[5]), m67 = fminf(sq[6], sq[7]);
        float mall = fminf(fminf(m01, m23), fminf(m45, m67));
        if (mall < best[0]) {
#pragma unroll
            for (int u = 0; u < 8; ++u) {
                if (sq[u] < best[0]) {
                    best[0] = sq[u]; bidx[0] = jj + u;
#pragma unroll
                    for (int i = 0; i < K_NN - 1; ++i) {
                        if (best[i] < best[i + 1]) {
                            float tb = best[i]; best[i] = best[i + 1]; best[i + 1] = tb;
                            int   ti = bidx[i]; bidx[i] = bidx[i + 1]; bidx[i + 1] = ti;
                        }
                    }
                }
            }
        }
    }

    // Publish partial top-10s.
#pragma unroll
    for (int i = 0; i < K_NN; ++i) {
        msq [tid * K_NN + i] = best[i];
        midx[tid * K_NN + i] = bidx[i];
    }
    __syncthreads();

    if (seg == 0) {
        // Merge the other 3 segments' candidates (nearest-first per list).
        for (int s = 1; s < SEG; ++s) {
            const int base = (s * 64 + qlane) * K_NN;
#pragma unroll
            for (int i = K_NN - 1; i >= 0; --i) {
                float v = msq[base + i];
                if (v < best[0]) {
                    best[0] = v; bidx[0] = midx[base + i];
#pragma unroll
                    for (int t = 0; t < K_NN - 1; ++t) {
                        if (best[t] < best[t + 1]) {
                            float tb = best[t]; best[t] = best[t + 1]; best[t + 1] = tb;
                            int   ti = bidx[t]; bidx[t] = bidx[t + 1]; bidx[t + 1] = ti;
                        }
                    }
                }
            }
        }

        // Inside/outside vote (grad normalization dropped: sign-preserving).
        int votes = 0;
#pragma unroll
        for (int i = 0; i < K_NN; ++i) {
            int j = bidx[i];
            float4 p = sref[j];
            float gx = p.x - qx, gy = p.y - qy, gz = p.z - qz;
            const float* np_ = points + (size_t)(r * N_PTS + j) * 6 + 3;
            votes += (np_[0] * gx + np_[1] * gy + np_[2] * gz > 0.0f) ? 1 : 0;
        }

        float d0 = sqrtf(fmaxf(best[K_NN - 1], 0.0f));
        float sd = (votes > 8) ? -d0 : d0;
        pair_sd[((size_t)q * NSLOT + rs) * N_PTS + nq] = sd;
    }
}

__global__ __launch_bounds__(256) void reduce_kernel(
        const float* __restrict__ points,
        const float* __restrict__ estT,
        const float* __restrict__ planeT,
        const float* __restrict__ pair_sd,
        float* __restrict__ out) {
    int i = blockIdx.x * blockDim.x + threadIdx.x;
    if (i >= M_OBJ * N_PTS) return;
    int m = i / N_PTS, n = i % N_PTS;

    float T[3][4];
    make_T(estT + m * 16, planeT, T);
    const float* p = points + (size_t)i * 6;
    float zpl = T[2][0] * p[0] + T[2][1] * p[1] + T[2][2] * p[2] + T[2][3];

    float sd = zpl;
#pragma unroll
    for (int rs = 0; rs < NSLOT; ++rs)
        sd = fminf(sd, pair_sd[((size_t)m * NSLOT + rs) * N_PTS + n]);

    out[i] = sd;
    out[M_OBJ * N_PTS + i] = (sd < -0.01f) ? 1.0f : 0.0f;
}

extern "C" void kernel_launch(void* const* d_in, const int* in_sizes, int n_in,
                              void* d_out, int out_size, void* d_ws, size_t ws_size,
                              hipStream_t stream) {
    const float* points = (const float*)d_in[0];   // [4][3072][6]
    const float* estT   = (const float*)d_in[1];   // [4][4][4]
    const float* planeT = (const float*)d_in[2];   // [4][4]

    float* pair_sd = (float*)d_ws;                 // [4][3][3072]

    dim3 gridB(M_OBJ * NSLOT, N_PTS / QPB);        // 12 x 48 = 576 blocks
    pair_kernel<<<gridB, 256, 0, stream>>>(points, estT, planeT, pair_sd);

    int total = M_OBJ * N_PTS;
    reduce_kernel<<<(total + 255) / 256, 256, 0, stream>>>(points, estT, planeT,
                                                           pair_sd, (float*)d_out);
}